// Round 1
// baseline (199.662 us; speedup 1.0000x reference)
//
#include <hip/hip_runtime.h>
#include <cstdint>

#define DEVI __device__ __forceinline__

using fx4 = __attribute__((ext_vector_type(4))) float;
using bf8 = __attribute__((ext_vector_type(8))) __bf16;
using s8v = __attribute__((ext_vector_type(8))) short;
typedef unsigned short u16;
typedef unsigned int u32;

DEVI float b2f(u16 u) { return __builtin_bit_cast(float, (u32)u << 16); }
DEVI u16 f2b(float f) {
  u32 u = __builtin_bit_cast(u32, f);
  return (u16)((u + 0x7fffu + ((u >> 16) & 1u)) >> 16);
}

// ---- fp32 -> bf16 weight conversion, 6 tensors in one launch ----
__global__ __launch_bounds__(256) void wcvt6(const float* s0, u16* d0, int n0,
                                             const float* s1, u16* d1, int n1,
                                             const float* s2, u16* d2, int n2,
                                             const float* s3, u16* d3, int n3,
                                             const float* s4, u16* d4, int n4,
                                             const float* s5, u16* d5, int n5) {
  const float* s; u16* d; int n;
  switch (blockIdx.y) {
    case 0: s = s0; d = d0; n = n0; break;
    case 1: s = s1; d = d1; n = n1; break;
    case 2: s = s2; d = d2; n = n2; break;
    case 3: s = s3; d = d3; n = n3; break;
    case 4: s = s4; d = d4; n = n4; break;
    default: s = s5; d = d5; n = n5; break;
  }
  int i = blockIdx.x * 256 + threadIdx.x;
  if (i < n) d[i] = f2b(s[i]);
}

// ---- concat + transpose: fd,fs [B,C,N] fp32 -> cat_t [B,N,2C] bf16 ----
__global__ void pack_cat(const float* __restrict__ fd, const float* __restrict__ fs,
                         u16* __restrict__ out) {
  __shared__ float t[32][33];
  const int b = blockIdx.z;
  const int n0 = blockIdx.x * 32;
  const int g = blockIdx.y;                 // 0..15
  const float* src = (g < 8) ? fd : fs;
  const int c0 = (g & 7) * 32;
  const int ccol0 = g * 32;                 // output channel col 0..511
  const int tx = threadIdx.x;               // 0..31
  const int ty = threadIdx.y;               // 0..7
  const float* sp = src + ((long)b * 256 + c0) * 4096 + n0;
#pragma unroll
  for (int i = 0; i < 4; ++i) {
    int c = ty + i * 8;
    t[c][tx] = sp[(long)c * 4096 + tx];
  }
  __syncthreads();
  u16* op = out + ((long)b * 4096 + n0) * 512 + ccol0;
#pragma unroll
  for (int i = 0; i < 4; ++i) {
    int r = ty + i * 8;
    op[(long)r * 512 + tx] = f2b(t[tx][r]);
  }
}

// ---- generic bf16 NT GEMM: C[m,n] = sum_k A[m,k]*B[n,k] (+bias[n]) ----
// 128x128 tile, BK=64, 4 waves, reg-staged LDS with XOR swizzle, split-K support.
template <typename OT, bool BIAS>
__global__ __launch_bounds__(256) void gemm_nt(
    const u16* __restrict__ A, long sA, int lda,
    const u16* __restrict__ B, long sB, int ldb,
    OT* __restrict__ C, long sC, long sCs, int ldc,
    const float* __restrict__ bias, int Keff, int ksplit) {
  __shared__ u16 ldsA[128 * 64];
  __shared__ u16 ldsB[128 * 64];
  const int z = blockIdx.z;
  const int bb = z / ksplit;
  const int ss = z - bb * ksplit;
  const int bm = blockIdx.x * 128;
  const int bn = blockIdx.y * 128;
  const u16* Ab = A + bb * sA + (long)ss * Keff;
  const u16* Bb = B + bb * sB + (long)ss * Keff;
  const int tid = threadIdx.x;
  const int wid = tid >> 6;
  const int lane = tid & 63;
  const int wm = wid >> 1, wn = wid & 1;
  const int r8 = lane >> 3, ch = lane & 7;

  fx4 acc[4][4] = {};
  for (int kt = 0; kt < Keff; kt += 64) {
    s8v ga[4], gb[4];
#pragma unroll
    for (int i = 0; i < 4; ++i) {
      const int row = wid * 32 + i * 8 + r8;
      ga[i] = *(const s8v*)&Ab[(long)(bm + row) * lda + kt + ch * 8];
      gb[i] = *(const s8v*)&Bb[(long)(bn + row) * ldb + kt + ch * 8];
    }
#pragma unroll
    for (int i = 0; i < 4; ++i) {
      const int row = wid * 32 + i * 8 + r8;
      const int sw = ((ch ^ (row & 7)) * 8);
      *(s8v*)&ldsA[row * 64 + sw] = ga[i];
      *(s8v*)&ldsB[row * 64 + sw] = gb[i];
    }
    __syncthreads();
#pragma unroll
    for (int ko = 0; ko < 2; ++ko) {
      bf8 af[4], bfr[4];
      const int kq = ko * 4 + (lane >> 4);
#pragma unroll
      for (int f = 0; f < 4; ++f) {
        const int ar = wm * 64 + f * 16 + (lane & 15);
        af[f] = *(const bf8*)&ldsA[ar * 64 + ((kq ^ (ar & 7)) * 8)];
        const int br = wn * 64 + f * 16 + (lane & 15);
        bfr[f] = *(const bf8*)&ldsB[br * 64 + ((kq ^ (br & 7)) * 8)];
      }
#pragma unroll
      for (int fm = 0; fm < 4; ++fm)
#pragma unroll
        for (int fn = 0; fn < 4; ++fn)
          acc[fm][fn] = __builtin_amdgcn_mfma_f32_16x16x32_bf16(af[fm], bfr[fn], acc[fm][fn], 0, 0, 0);
    }
    __syncthreads();
  }
  OT* Cb = C + bb * sC + ss * sCs;
#pragma unroll
  for (int fm = 0; fm < 4; ++fm) {
    const int m0 = bm + wm * 64 + fm * 16 + ((lane >> 4) << 2);
#pragma unroll
    for (int fn = 0; fn < 4; ++fn) {
      const int n0 = bn + wn * 64 + fn * 16 + (lane & 15);
      float bv = 0.f;
      if (BIAS) bv = bias[n0];
#pragma unroll
      for (int r = 0; r < 4; ++r) {
        float v = acc[fm][fn][r] + bv;
        if constexpr (sizeof(OT) == 2) Cb[(long)(m0 + r) * ldc + n0] = (OT)f2b(v);
        else Cb[(long)(m0 + r) * ldc + n0] = v;
      }
    }
  }
}

// ---- depthwise 3x3 SAME, [B,N,C] bf16 layout ----
__global__ __launch_bounds__(256) void dwconv3x3(const u16* __restrict__ x,
                                                 const float* __restrict__ wdw,
                                                 u16* __restrict__ y) {
  __shared__ float w[9][256];
  const int t = threadIdx.x;
  for (int i = t; i < 2304; i += 256) w[i % 9][i / 9] = wdw[i];
  __syncthreads();
  const int nb = blockIdx.x;
  const int b = nb >> 9;
  const int n0 = (nb & 511) << 3;
  const int tn = t >> 5;
  const int tc = (t & 31) << 3;
  const int n = n0 + tn;
  const int hh = n >> 6, ww2 = n & 63;
  const u16* base = x + ((long)b << 20);
  float acc[8] = {0.f, 0.f, 0.f, 0.f, 0.f, 0.f, 0.f, 0.f};
#pragma unroll
  for (int ky = 0; ky < 3; ++ky) {
    const int hy = hh + ky - 1;
    if ((unsigned)hy >= 64u) continue;
#pragma unroll
    for (int kx = 0; kx < 3; ++kx) {
      const int wx = ww2 + kx - 1;
      if ((unsigned)wx >= 64u) continue;
      const s8v v = *(const s8v*)&base[(((hy << 6) + wx) << 8) + tc];
      const int kk = ky * 3 + kx;
      const fx4 wa = *(const fx4*)&w[kk][tc];
      const fx4 wb = *(const fx4*)&w[kk][tc + 4];
#pragma unroll
      for (int j = 0; j < 4; ++j) {
        acc[j] += wa[j] * b2f((u16)v[j]);
        acc[4 + j] += wb[j] * b2f((u16)v[4 + j]);
      }
    }
  }
  s8v o;
#pragma unroll
  for (int j = 0; j < 8; ++j) o[j] = (short)f2b(acc[j]);
  *(s8v*)&y[((long)b << 20) + ((long)n << 8) + tc] = o;
}

// ---- in-place row L2 normalize, rows of 4096 bf16 ----
__global__ __launch_bounds__(256) void l2norm_rows(u16* __restrict__ buf) {
  const long row = blockIdx.x;
  u16* p = buf + row * 4096;
  const int t = threadIdx.x;
  s8v a = ((s8v*)p)[t * 2];
  s8v b = ((s8v*)p)[t * 2 + 1];
  float ss = 0.f;
#pragma unroll
  for (int j = 0; j < 8; ++j) {
    float xa = b2f((u16)a[j]); ss += xa * xa;
    float xb = b2f((u16)b[j]); ss += xb * xb;
  }
#pragma unroll
  for (int o = 32; o > 0; o >>= 1) ss += __shfl_xor(ss, o);
  __shared__ float red[4];
  if ((t & 63) == 0) red[t >> 6] = ss;
  __syncthreads();
  const float tot = red[0] + red[1] + red[2] + red[3];
  const float sc = 1.f / fmaxf(sqrtf(tot), 1e-12f);
#pragma unroll
  for (int j = 0; j < 8; ++j) {
    a[j] = (short)f2b(b2f((u16)a[j]) * sc);
    b[j] = (short)f2b(b2f((u16)b[j]) * sc);
  }
  ((s8v*)p)[t * 2] = a;
  ((s8v*)p)[t * 2 + 1] = b;
}

// ---- sum split-K partials + row softmax (rows of 256), fp32 -> bf16 ----
__global__ __launch_bounds__(256) void softmax_splits(const float* __restrict__ part,
                                                      u16* __restrict__ out,
                                                      int nsplit, long sstride) {
  const int wid = threadIdx.x >> 6, lane = threadIdx.x & 63;
  const long row = (long)blockIdx.x * 4 + wid;
  fx4 v = {0.f, 0.f, 0.f, 0.f};
  for (int s = 0; s < nsplit; ++s)
    v += ((const fx4*)(part + s * sstride + row * 256))[lane];
  float m = fmaxf(fmaxf(v[0], v[1]), fmaxf(v[2], v[3]));
#pragma unroll
  for (int o = 32; o > 0; o >>= 1) m = fmaxf(m, __shfl_xor(m, o));
  float e0 = __expf(v[0] - m), e1 = __expf(v[1] - m);
  float e2 = __expf(v[2] - m), e3 = __expf(v[3] - m);
  float s4 = e0 + e1 + e2 + e3;
#pragma unroll
  for (int o = 32; o > 0; o >>= 1) s4 += __shfl_xor(s4, o);
  const float inv = 1.f / s4;
  u16* op = out + row * 256 + lane * 4;
  op[0] = f2b(e0 * inv); op[1] = f2b(e1 * inv);
  op[2] = f2b(e2 * inv); op[3] = f2b(e3 * inv);
}

// ---- row mean, rows of 4096 fp32 ----
__global__ __launch_bounds__(256) void rowmean(const float* __restrict__ x, float* __restrict__ pooled) {
  const long row = blockIdx.x;
  const fx4* p = (const fx4*)(x + row * 4096);
  const int t = threadIdx.x;
  float s = 0.f;
#pragma unroll
  for (int i = 0; i < 4; ++i) {
    fx4 v = p[t * 4 + i];
    s += v[0] + v[1] + v[2] + v[3];
  }
#pragma unroll
  for (int o = 32; o > 0; o >>= 1) s += __shfl_xor(s, o);
  __shared__ float red[4];
  if ((t & 63) == 0) red[t >> 6] = s;
  __syncthreads();
  if (t == 0) pooled[row] = (red[0] + red[1] + red[2] + red[3]) * (1.f / 4096.f);
}

// ---- SE gate MLPs (both branches), one block per batch ----
__global__ __launch_bounds__(256) void se_gates(const float* __restrict__ pooled,
                                                const float* __restrict__ w1d, const float* __restrict__ w2d,
                                                const float* __restrict__ w1s, const float* __restrict__ w2s,
                                                float* __restrict__ gd, float* __restrict__ gs) {
  const int b = blockIdx.x;
  const int t = threadIdx.x;
  __shared__ float p[256], hd[16], hs[16];
  p[t] = pooled[b * 256 + t];
  __syncthreads();
  if (t < 16) {
    float ad = 0.f, as2 = 0.f;
    for (int j = 0; j < 256; ++j) {
      ad += w1d[t * 256 + j] * p[j];
      as2 += w1s[t * 256 + j] * p[j];
    }
    hd[t] = fmaxf(ad, 0.f);
    hs[t] = fmaxf(as2, 0.f);
  }
  __syncthreads();
  float ad = 0.f, as2 = 0.f;
#pragma unroll
  for (int r = 0; r < 16; ++r) {
    ad += w2d[t * 16 + r] * hd[r];
    as2 += w2s[t * 16 + r] * hs[r];
  }
  gd[b * 256 + t] = 1.f / (1.f + __expf(-ad));
  gs[b * 256 + t] = 1.f / (1.f + __expf(-as2));
}

// ---- final: out = out_c * gate + residual, both branches ----
__global__ __launch_bounds__(256) void fuse_out(const float* __restrict__ oc,
                                                const float* __restrict__ gd, const float* __restrict__ gs,
                                                const float* __restrict__ fd, const float* __restrict__ fs,
                                                float* __restrict__ od, float* __restrict__ os) {
  const long i = ((long)blockIdx.x * 256 + threadIdx.x) * 4;
  const long bc = i >> 12;
  const float gdv = gd[bc], gsv = gs[bc];
  const fx4 c = *(const fx4*)(oc + i);
  const fx4 a = *(const fx4*)(fd + i);
  const fx4 s = *(const fx4*)(fs + i);
  *(fx4*)(od + i) = c * gdv + a;
  *(fx4*)(os + i) = c * gsv + s;
}

extern "C" void kernel_launch(void* const* d_in, const int* in_sizes, int n_in,
                              void* d_out, int out_size, void* d_ws, size_t ws_size,
                              hipStream_t stream) {
  const float* fd  = (const float*)d_in[0];
  const float* fs  = (const float*)d_in[1];
  const float* W0  = (const float*)d_in[2];
  const float* Wdw = (const float*)d_in[3];
  const float* Wq  = (const float*)d_in[4];
  const float* Wk  = (const float*)d_in[5];
  const float* Wv  = (const float*)d_in[6];
  const float* Wp  = (const float*)d_in[7];
  const float* bp  = (const float*)d_in[8];
  const float* Wsp = (const float*)d_in[9];
  const float* w1d = (const float*)d_in[10];
  const float* w2d = (const float*)d_in[11];
  const float* w1s = (const float*)d_in[12];
  const float* w2s = (const float*)d_in[13];

  char* ws = (char*)d_ws;
  // region map (bytes): lifetimes guarantee no overlap of live data
  u16* catb  = (u16*)(ws + 0);           // [B,N,512] bf16, 32MB; dead after conv0
  u16* qb    = (u16*)(ws + 0);           // [B,C,N] bf16 16MB (reuses cat)
  u16* kb    = (u16*)(ws + 16777216);    // [B,C,N] bf16 16MB (reuses cat)
  u16* x0b   = (u16*)(ws + 33554432);    // [B,N,C] bf16 16MB; dead after dw
  u16* ytb   = x0b;                      // [B,N,C] bf16 (reuse)
  u16* xtb   = (u16*)(ws + 50331648);    // [B,N,C] bf16 16MB; dead after v gemm
  u16* zb    = xtb;                      // [B,N,C] bf16 (reuse)
  u16* vtb   = (u16*)(ws + 67108864);    // [B,N,C] bf16 16MB
  u16* asmb  = (u16*)(ws + 83886080);    // [B,C,C] bf16 1MB
  float* outc = (float*)(ws + 84934656); // [B,C,N] fp32 33.5MB
  float* part = outc;                    // attn split-K partials [8][B,C,C] fp32 16MB (dead before outc written)
  u16* w0b = (u16*)(ws + 118489088);
  u16* wqb = w0b + 131072;
  u16* wkb = wqb + 65536;
  u16* wvb = wkb + 65536;
  u16* wpb = wvb + 65536;
  u16* wsb = wpb + 65536;
  float* pooled = (float*)(ws + 119406592);
  float* gdp    = (float*)(ws + 119414784);
  float* gsp    = (float*)(ws + 119422976);
  float* od  = (float*)d_out;
  float* osg = od + 8388608;

  wcvt6<<<dim3(512, 6), 256, 0, stream>>>(W0, w0b, 131072, Wq, wqb, 65536, Wk, wkb, 65536,
                                          Wv, wvb, 65536, Wp, wpb, 65536, Wsp, wsb, 65536);
  pack_cat<<<dim3(128, 16, 8), dim3(32, 8), 0, stream>>>(fd, fs, catb);
  // conv0: x0[b,n,o] = sum_c cat[b,n,c] W0[o,c]   M=4096 N=256 K=512
  gemm_nt<u16, false><<<dim3(32, 2, 8), 256, 0, stream>>>(catb, 2097152, 512, w0b, 0, 512,
                                                          x0b, 1048576, 0, 256, nullptr, 512, 1);
  dwconv3x3<<<4096, 256, 0, stream>>>(x0b, Wdw, xtb);
  // q[b,c,n] = sum_d Wq[c,d] xt[b,n,d]   M=256 N=4096 K=256
  gemm_nt<u16, false><<<dim3(2, 32, 8), 256, 0, stream>>>(wqb, 0, 256, xtb, 1048576, 256,
                                                          qb, 1048576, 0, 4096, nullptr, 256, 1);
  gemm_nt<u16, false><<<dim3(2, 32, 8), 256, 0, stream>>>(wkb, 0, 256, xtb, 1048576, 256,
                                                          kb, 1048576, 0, 4096, nullptr, 256, 1);
  // vt[b,n,c] = sum_d xt[b,n,d] Wv[c,d]   M=4096 N=256 K=256
  gemm_nt<u16, false><<<dim3(32, 2, 8), 256, 0, stream>>>(xtb, 1048576, 256, wvb, 0, 256,
                                                          vtb, 1048576, 0, 256, nullptr, 256, 1);
  l2norm_rows<<<2048, 256, 0, stream>>>(qb);
  l2norm_rows<<<2048, 256, 0, stream>>>(kb);
  // attn[b,c,d] = sum_n k[b,c,n] q[b,d,n]   M=256 N=256 K=4096, split-K x8
  gemm_nt<float, false><<<dim3(2, 2, 64), 256, 0, stream>>>(kb, 1048576, 4096, qb, 1048576, 4096,
                                                            part, 65536, 524288, 256, nullptr, 512, 8);
  softmax_splits<<<512, 256, 0, stream>>>(part, asmb, 8, 524288);
  // yt[b,n,c] = sum_d vt[b,n,d] attn[b,c,d]   M=4096 N=256 K=256
  gemm_nt<u16, false><<<dim3(32, 2, 8), 256, 0, stream>>>(vtb, 1048576, 256, asmb, 65536, 256,
                                                          ytb, 1048576, 0, 256, nullptr, 256, 1);
  // z[b,n,c] = sum_d yt[b,n,d] Wp[c,d] + bp[c]
  gemm_nt<u16, true><<<dim3(32, 2, 8), 256, 0, stream>>>(ytb, 1048576, 256, wpb, 0, 256,
                                                         zb, 1048576, 0, 256, bp, 256, 1);
  // out_c[b,o,n] = sum_c Wsplit[o,c] z[b,n,c]   M=256 N=4096 K=256
  gemm_nt<float, false><<<dim3(2, 32, 8), 256, 0, stream>>>(wsb, 0, 256, zb, 1048576, 256,
                                                            outc, 1048576, 0, 4096, nullptr, 256, 1);
  rowmean<<<2048, 256, 0, stream>>>(outc, pooled);
  se_gates<<<8, 256, 0, stream>>>(pooled, w1d, w2d, w1s, w2s, gdp, gsp);
  fuse_out<<<8192, 256, 0, stream>>>(outc, gdp, gsp, fd, fs, od, osg);
}

// Round 2
// 179.355 us; speedup vs baseline: 1.1132x; 1.1132x over previous
//
#include <hip/hip_runtime.h>
#include <cstdint>

#define DEVI __device__ __forceinline__

using fx4 = __attribute__((ext_vector_type(4))) float;
using bf8 = __attribute__((ext_vector_type(8))) __bf16;
using s8v = __attribute__((ext_vector_type(8))) short;
typedef unsigned short u16;
typedef unsigned int u32;

DEVI float b2f(u16 u) { return __builtin_bit_cast(float, (u32)u << 16); }
DEVI u16 f2b(float f) {
  u32 u = __builtin_bit_cast(u32, f);
  return (u16)((u + 0x7fffu + ((u >> 16) & 1u)) >> 16);
}

// async global->LDS, 16B per lane, dest = wave-uniform base + lane*16
#define GLOAD(g, l)                                                          \
  __builtin_amdgcn_global_load_lds(                                          \
      (const __attribute__((address_space(1))) unsigned int*)(g),            \
      (__attribute__((address_space(3))) unsigned int*)(l), 16, 0, 0)

// ---- fp32 -> bf16 weight conversion: W0, Wq, Wk, Wv ----
__global__ __launch_bounds__(256) void wcvt(const float* s0, u16* d0, int n0,
                                            const float* s1, u16* d1, int n1,
                                            const float* s2, u16* d2, int n2,
                                            const float* s3, u16* d3, int n3) {
  const float* s; u16* d; int n;
  switch (blockIdx.y) {
    case 0: s = s0; d = d0; n = n0; break;
    case 1: s = s1; d = d1; n = n1; break;
    case 2: s = s2; d = d2; n = n2; break;
    default: s = s3; d = d3; n = n3; break;
  }
  int i = blockIdx.x * 256 + threadIdx.x;
  if (i < n) d[i] = f2b(s[i]);
}

// ---- Wc = Wsp @ Wp (bf16), bc = Wsp @ bp (fp32); one block per output row o ----
__global__ __launch_bounds__(256) void wcmul(const float* __restrict__ Wsp,
                                             const float* __restrict__ Wp,
                                             const float* __restrict__ bp,
                                             u16* __restrict__ wcb, float* __restrict__ bc) {
  const int o = blockIdx.x, t = threadIdx.x;
  __shared__ float row[256];
  __shared__ float red[4];
  row[t] = Wsp[o * 256 + t];
  __syncthreads();
  float acc = 0.f;
  for (int c = 0; c < 256; ++c) acc += row[c] * Wp[c * 256 + t];
  wcb[o * 256 + t] = f2b(acc);
  float pb = row[t] * bp[t];
#pragma unroll
  for (int m = 32; m > 0; m >>= 1) pb += __shfl_xor(pb, m);
  if ((t & 63) == 0) red[t >> 6] = pb;
  __syncthreads();
  if (t == 0) bc[o] = red[0] + red[1] + red[2] + red[3];
}

// ---- concat + transpose: fd,fs [B,C,N] fp32 -> cat_t [B,N,2C] bf16 ----
__global__ void pack_cat(const float* __restrict__ fd, const float* __restrict__ fs,
                         u16* __restrict__ out) {
  __shared__ float t[32][33];
  const int b = blockIdx.z;
  const int n0 = blockIdx.x * 32;
  const int g = blockIdx.y;                 // 0..15
  const float* src = (g < 8) ? fd : fs;
  const int c0 = (g & 7) * 32;
  const int ccol0 = g * 32;
  const int tx = threadIdx.x;               // 0..31
  const int ty = threadIdx.y;               // 0..7
  const float* sp = src + ((long)b * 256 + c0) * 4096 + n0;
#pragma unroll
  for (int i = 0; i < 4; ++i) {
    int c = ty + i * 8;
    t[c][tx] = sp[(long)c * 4096 + tx];
  }
  __syncthreads();
  u16* op = out + ((long)b * 4096 + n0) * 512 + ccol0;
#pragma unroll
  for (int i = 0; i < 4; ++i) {
    int r = ty + i * 8;
    op[(long)r * 512 + tx] = f2b(t[tx][r]);
  }
}

// ---- bf16 NT GEMM: C[m,n] = sum_k A[m,k]*B[n,k] ----
// 128x128 tile, BK=64, 4 waves; global_load_lds(16B) staging with
// pre-swizzled SOURCE address (LDS dest linear, XOR-swizzled read).
// BIAS: 0 none, 1 bias[n], 2 bias[m]. POOL: also emit per-tile row sums.
template <typename OT, int BIAS, bool POOL>
__global__ __launch_bounds__(256) void gemm_nt(
    const u16* __restrict__ A, long sA, int lda,
    const u16* __restrict__ B, long sB, int ldb,
    OT* __restrict__ C, long sC, long sCs, int ldc,
    const float* __restrict__ bias, int Keff, int ksplit,
    float* __restrict__ poolpart) {
  __shared__ u16 ldsA[128 * 64];
  __shared__ u16 ldsB[128 * 64];
  const int z = blockIdx.z;
  const int bb = z / ksplit;
  const int ss = z - bb * ksplit;
  const int bm = blockIdx.x * 128;
  const int bn = blockIdx.y * 128;
  const u16* Ab = A + bb * sA + (long)ss * Keff + (long)bm * lda;
  const u16* Bb = B + bb * sB + (long)ss * Keff + (long)bn * ldb;
  const int tid = threadIdx.x;
  const int wid = tid >> 6;
  const int lane = tid & 63;
  const int wm = wid >> 1, wn = wid & 1;
  const int srow = tid >> 3;                 // 0..31
  const int slot = tid & 7;

  fx4 acc[4][4] = {};
  for (int kt = 0; kt < Keff; kt += 64) {
#pragma unroll
    for (int i = 0; i < 4; ++i) {
      const int row = i * 32 + srow;
      const int kq = slot ^ (row & 7);       // inverse-swizzled source chunk
      GLOAD(Ab + (long)row * lda + kt + kq * 8, &ldsA[i * 2048 + wid * 512]);
      GLOAD(Bb + (long)row * ldb + kt + kq * 8, &ldsB[i * 2048 + wid * 512]);
    }
    __syncthreads();                          // drains vmcnt
#pragma unroll
    for (int ko = 0; ko < 2; ++ko) {
      bf8 af[4], bfr[4];
      const int kq = ko * 4 + (lane >> 4);
#pragma unroll
      for (int f = 0; f < 4; ++f) {
        const int ar = wm * 64 + f * 16 + (lane & 15);
        af[f] = *(const bf8*)&ldsA[ar * 64 + ((kq ^ (ar & 7)) * 8)];
        const int br = wn * 64 + f * 16 + (lane & 15);
        bfr[f] = *(const bf8*)&ldsB[br * 64 + ((kq ^ (br & 7)) * 8)];
      }
#pragma unroll
      for (int fm = 0; fm < 4; ++fm)
#pragma unroll
        for (int fn = 0; fn < 4; ++fn)
          acc[fm][fn] = __builtin_amdgcn_mfma_f32_16x16x32_bf16(af[fm], bfr[fn], acc[fm][fn], 0, 0, 0);
    }
    __syncthreads();
  }
  OT* Cb = C + bb * sC + ss * sCs;
  float pr[4][4];
  if (POOL) {
#pragma unroll
    for (int fm = 0; fm < 4; ++fm)
#pragma unroll
      for (int r = 0; r < 4; ++r) pr[fm][r] = 0.f;
  }
#pragma unroll
  for (int fm = 0; fm < 4; ++fm) {
    const int m0 = bm + wm * 64 + fm * 16 + ((lane >> 4) << 2);
#pragma unroll
    for (int fn = 0; fn < 4; ++fn) {
      const int n0 = bn + wn * 64 + fn * 16 + (lane & 15);
      float bvn = (BIAS == 1) ? bias[n0] : 0.f;
#pragma unroll
      for (int r = 0; r < 4; ++r) {
        float v = acc[fm][fn][r] + bvn;
        if (BIAS == 2) v += bias[m0 + r];
        if constexpr (sizeof(OT) == 2) Cb[(long)(m0 + r) * ldc + n0] = (OT)f2b(v);
        else Cb[(long)(m0 + r) * ldc + n0] = v;
        if (POOL) pr[fm][r] += v;
      }
    }
  }
  if (POOL) {
#pragma unroll
    for (int fm = 0; fm < 4; ++fm)
#pragma unroll
      for (int r = 0; r < 4; ++r) {
        float s = pr[fm][r];
        s += __shfl_xor(s, 1); s += __shfl_xor(s, 2);
        s += __shfl_xor(s, 4); s += __shfl_xor(s, 8);
        if ((lane & 15) == 0) {
          const int o = bm + wm * 64 + fm * 16 + ((lane >> 4) << 2) + r;
          poolpart[(long)(blockIdx.y * 2 + wn) * 2048 + bb * 256 + o] = s;
        }
      }
  }
}

// ---- depthwise 3x3 SAME, [B,N,C] bf16 layout ----
__global__ __launch_bounds__(256) void dwconv3x3(const u16* __restrict__ x,
                                                 const float* __restrict__ wdw,
                                                 u16* __restrict__ y) {
  __shared__ float w[9][256];
  const int t = threadIdx.x;
  for (int i = t; i < 2304; i += 256) w[i % 9][i / 9] = wdw[i];
  __syncthreads();
  const int nb = blockIdx.x;
  const int b = nb >> 9;
  const int n0 = (nb & 511) << 3;
  const int tn = t >> 5;
  const int tc = (t & 31) << 3;
  const int n = n0 + tn;
  const int hh = n >> 6, ww2 = n & 63;
  const u16* base = x + ((long)b << 20);
  float acc[8] = {0.f, 0.f, 0.f, 0.f, 0.f, 0.f, 0.f, 0.f};
#pragma unroll
  for (int ky = 0; ky < 3; ++ky) {
    const int hy = hh + ky - 1;
    if ((unsigned)hy >= 64u) continue;
#pragma unroll
    for (int kx = 0; kx < 3; ++kx) {
      const int wx = ww2 + kx - 1;
      if ((unsigned)wx >= 64u) continue;
      const s8v v = *(const s8v*)&base[(((hy << 6) + wx) << 8) + tc];
      const int kk = ky * 3 + kx;
      const fx4 wa = *(const fx4*)&w[kk][tc];
      const fx4 wb = *(const fx4*)&w[kk][tc + 4];
#pragma unroll
      for (int j = 0; j < 4; ++j) {
        acc[j] += wa[j] * b2f((u16)v[j]);
        acc[4 + j] += wb[j] * b2f((u16)v[4 + j]);
      }
    }
  }
  s8v o;
#pragma unroll
  for (int j = 0; j < 8; ++j) o[j] = (short)f2b(acc[j]);
  *(s8v*)&y[((long)b << 20) + ((long)n << 8) + tc] = o;
}

// ---- per-row inverse L2 norm: rows of 4096 bf16 -> rinv[row] ----
__global__ __launch_bounds__(256) void rownorm(const u16* __restrict__ qk,
                                               float* __restrict__ rinv) {
  const long row = blockIdx.x;
  const u16* p = qk + row * 4096;
  const int t = threadIdx.x;
  float ss = 0.f;
#pragma unroll
  for (int c = 0; c < 2; ++c) {
    s8v a = ((const s8v*)p)[t * 2 + c];
#pragma unroll
    for (int j = 0; j < 8; ++j) { float x = b2f((u16)a[j]); ss += x * x; }
  }
#pragma unroll
  for (int o = 32; o > 0; o >>= 1) ss += __shfl_xor(ss, o);
  __shared__ float red[4];
  if ((t & 63) == 0) red[t >> 6] = ss;
  __syncthreads();
  if (t == 0) rinv[row] = 1.f / fmaxf(sqrtf(red[0] + red[1] + red[2] + red[3]), 1e-12f);
}

// ---- sum split-K partials, apply norm scales, row softmax -> bf16 ----
__global__ __launch_bounds__(256) void softmax_splits(const float* __restrict__ part,
                                                      const float* __restrict__ rinv,
                                                      u16* __restrict__ out) {
  const int wid = threadIdx.x >> 6, lane = threadIdx.x & 63;
  const long row = (long)blockIdx.x * 4 + wid;   // b*256 + c
  const int b = (int)(row >> 8);
  const int c = (int)(row & 255);
  fx4 v = {0.f, 0.f, 0.f, 0.f};
#pragma unroll
  for (int s = 0; s < 8; ++s)
    v += ((const fx4*)(part + s * 524288 + row * 256))[lane];
  const float rk = rinv[b * 512 + 256 + c];
  const fx4 rq = *(const fx4*)&rinv[b * 512 + lane * 4];
  v[0] *= rk * rq[0]; v[1] *= rk * rq[1]; v[2] *= rk * rq[2]; v[3] *= rk * rq[3];
  float m = fmaxf(fmaxf(v[0], v[1]), fmaxf(v[2], v[3]));
#pragma unroll
  for (int o = 32; o > 0; o >>= 1) m = fmaxf(m, __shfl_xor(m, o));
  float e0 = __expf(v[0] - m), e1 = __expf(v[1] - m);
  float e2 = __expf(v[2] - m), e3 = __expf(v[3] - m);
  float s4 = e0 + e1 + e2 + e3;
#pragma unroll
  for (int o = 32; o > 0; o >>= 1) s4 += __shfl_xor(s4, o);
  const float inv = 1.f / s4;
  u16* op = out + row * 256 + lane * 4;
  op[0] = f2b(e0 * inv); op[1] = f2b(e1 * inv);
  op[2] = f2b(e2 * inv); op[3] = f2b(e3 * inv);
}

// ---- SE gates: sum pooled partials + 2-layer MLP, both branches ----
__global__ __launch_bounds__(256) void se_gates(const float* __restrict__ poolpart,
                                                const float* __restrict__ w1d, const float* __restrict__ w2d,
                                                const float* __restrict__ w1s, const float* __restrict__ w2s,
                                                float* __restrict__ gd, float* __restrict__ gs) {
  const int b = blockIdx.x;
  const int t = threadIdx.x;
  __shared__ float p[256], hd[16], hs[16];
  float s = 0.f;
#pragma unroll 8
  for (int sl = 0; sl < 64; ++sl) s += poolpart[(long)sl * 2048 + b * 256 + t];
  p[t] = s * (1.f / 4096.f);
  __syncthreads();
  if (t < 16) {
    float ad = 0.f, as2 = 0.f;
    for (int j = 0; j < 256; ++j) {
      ad += w1d[t * 256 + j] * p[j];
      as2 += w1s[t * 256 + j] * p[j];
    }
    hd[t] = fmaxf(ad, 0.f);
    hs[t] = fmaxf(as2, 0.f);
  }
  __syncthreads();
  float ad = 0.f, as2 = 0.f;
#pragma unroll
  for (int r = 0; r < 16; ++r) {
    ad += w2d[t * 16 + r] * hd[r];
    as2 += w2s[t * 16 + r] * hs[r];
  }
  gd[b * 256 + t] = 1.f / (1.f + __expf(-ad));
  gs[b * 256 + t] = 1.f / (1.f + __expf(-as2));
}

// ---- final: out = outc(bf16) * gate + residual, both branches ----
__global__ __launch_bounds__(256) void fuse_out(const u16* __restrict__ oc,
                                                const float* __restrict__ gd, const float* __restrict__ gs,
                                                const float* __restrict__ fd, const float* __restrict__ fs,
                                                float* __restrict__ od, float* __restrict__ os) {
  const long i = ((long)blockIdx.x * 256 + threadIdx.x) * 8;
  const long bc = i >> 12;
  const float gdv = gd[bc], gsv = gs[bc];
  const s8v c8 = *(const s8v*)&oc[i];
  const fx4 a0 = *(const fx4*)(fd + i), a1 = *(const fx4*)(fd + i + 4);
  const fx4 s0 = *(const fx4*)(fs + i), s1 = *(const fx4*)(fs + i + 4);
  fx4 d0, d1, e0, e1;
#pragma unroll
  for (int j = 0; j < 4; ++j) {
    const float cl = b2f((u16)c8[j]);
    const float ch = b2f((u16)c8[4 + j]);
    d0[j] = cl * gdv + a0[j]; d1[j] = ch * gdv + a1[j];
    e0[j] = cl * gsv + s0[j]; e1[j] = ch * gsv + s1[j];
  }
  *(fx4*)(od + i) = d0; *(fx4*)(od + i + 4) = d1;
  *(fx4*)(os + i) = e0; *(fx4*)(os + i + 4) = e1;
}

extern "C" void kernel_launch(void* const* d_in, const int* in_sizes, int n_in,
                              void* d_out, int out_size, void* d_ws, size_t ws_size,
                              hipStream_t stream) {
  const float* fd  = (const float*)d_in[0];
  const float* fs  = (const float*)d_in[1];
  const float* W0  = (const float*)d_in[2];
  const float* Wdw = (const float*)d_in[3];
  const float* Wq  = (const float*)d_in[4];
  const float* Wk  = (const float*)d_in[5];
  const float* Wv  = (const float*)d_in[6];
  const float* Wp  = (const float*)d_in[7];
  const float* bp  = (const float*)d_in[8];
  const float* Wsp = (const float*)d_in[9];
  const float* w1d = (const float*)d_in[10];
  const float* w2d = (const float*)d_in[11];
  const float* w1s = (const float*)d_in[12];
  const float* w2s = (const float*)d_in[13];

  char* ws = (char*)d_ws;
  u16* catb   = (u16*)(ws + 0);            // [B,N,512] bf16 32MB; dead after conv0
  u16* qkb    = catb;                      // [B,512,N] bf16 32MB (q rows 0-255, k rows 256-511)
  u16* x0b    = (u16*)(ws + 33554432);     // [B,N,256] bf16 16MB; dead after dwconv
  u16* ytb    = x0b;                       // [B,N,256] (reuse)
  u16* xtb    = (u16*)(ws + 50331648);     // [B,N,256] bf16 16MB; dead after v GEMM
  u16* outcb  = xtb;                       // [B,256,N] bf16 16MB (reuse)
  u16* vtb    = (u16*)(ws + 67108864);     // [B,N,256] bf16 16MB
  u16* asmb   = (u16*)(ws + 83886080);     // [B,256,256] bf16 1MB
  float* part = (float*)(ws + 84934656);   // [8][B,256,256] fp32 16.7MB
  u16* w0b    = (u16*)(ws + 101711872);    // 131072 el
  u16* wqkb   = (u16*)(ws + 101974016);    // 131072 el (Wq;Wk stacked)
  u16* wvb    = (u16*)(ws + 102236160);    // 65536 el
  u16* wcb    = (u16*)(ws + 102367232);    // 65536 el (Wsp@Wp)
  float* bcb  = (float*)(ws + 102498304);  // 256
  float* rinv = (float*)(ws + 102499328);  // [B,512]
  float* poolpart = (float*)(ws + 102515712); // [64][B,256] fp32
  float* gdp  = (float*)(ws + 103040000);
  float* gsp  = (float*)(ws + 103048192);
  float* od  = (float*)d_out;
  float* osg = od + 8388608;

  wcvt<<<dim3(512, 4), 256, 0, stream>>>(W0, w0b, 131072, Wq, wqkb, 65536,
                                         Wk, wqkb + 65536, 65536, Wv, wvb, 65536);
  wcmul<<<256, 256, 0, stream>>>(Wsp, Wp, bp, wcb, bcb);
  pack_cat<<<dim3(128, 16, 8), dim3(32, 8), 0, stream>>>(fd, fs, catb);
  // conv0: x0[b,n,o] = sum_c cat[b,n,c] W0[o,c]   M=4096 N=256 K=512
  gemm_nt<u16, 0, false><<<dim3(32, 2, 8), 256, 0, stream>>>(
      catb, 2097152, 512, w0b, 0, 512, x0b, 1048576, 0, 256, nullptr, 512, 1, nullptr);
  dwconv3x3<<<4096, 256, 0, stream>>>(x0b, Wdw, xtb);
  // q;k [b,c512,n] = sum_d Wqk[c,d] xt[b,n,d]   M=512 N=4096 K=256
  gemm_nt<u16, 0, false><<<dim3(4, 32, 8), 256, 0, stream>>>(
      wqkb, 0, 256, xtb, 1048576, 256, qkb, 2097152, 0, 4096, nullptr, 256, 1, nullptr);
  // vt[b,n,c] = sum_d xt[b,n,d] Wv[c,d]   M=4096 N=256 K=256
  gemm_nt<u16, 0, false><<<dim3(32, 2, 8), 256, 0, stream>>>(
      xtb, 1048576, 256, wvb, 0, 256, vtb, 1048576, 0, 256, nullptr, 256, 1, nullptr);
  rownorm<<<4096, 256, 0, stream>>>(qkb, rinv);
  // raw attn[b,c,d] = sum_n k[b,c,n] q[b,d,n]   M=256 N=256 K=4096, split-K x8
  gemm_nt<float, 0, false><<<dim3(2, 2, 64), 256, 0, stream>>>(
      qkb + 1048576, 2097152, 4096, qkb, 2097152, 4096,
      part, 65536, 524288, 256, nullptr, 512, 8, nullptr);
  softmax_splits<<<512, 256, 0, stream>>>(part, rinv, asmb);
  // yt[b,n,c] = sum_d vt[b,n,d] attn[c,d]   M=4096 N=256 K=256
  gemm_nt<u16, 0, false><<<dim3(32, 2, 8), 256, 0, stream>>>(
      vtb, 1048576, 256, asmb, 65536, 256, ytb, 1048576, 0, 256, nullptr, 256, 1, nullptr);
  // outc[b,o,n] = sum_d Wc[o,d] yt[b,n,d] + bc[o]   M=256 N=4096 K=256, +pool partials
  gemm_nt<u16, 2, true><<<dim3(2, 32, 8), 256, 0, stream>>>(
      wcb, 0, 256, ytb, 1048576, 256, outcb, 1048576, 0, 4096, bcb, 256, 1, poolpart);
  se_gates<<<8, 256, 0, stream>>>(poolpart, w1d, w2d, w1s, w2s, gdp, gsp);
  fuse_out<<<4096, 256, 0, stream>>>(outcb, gdp, gsp, fd, fs, od, osg);
}